// Round 8
// baseline (237.021 us; speedup 1.0000x reference)
//
#include <hip/hip_runtime.h>
#include <hip/hip_bf16.h>

// Problem constants (from reference)
#define T_DIM   16
#define N_NODES 10000
#define FIN     32
#define FH      64
#define NE      160000
#define TB      2              // timesteps per chunk
#define NCHUNK  (T_DIM / TB)   // 8 chunks -> one per XCD via bid%8
#define NF      (N_NODES * FIN)

// ---------------------------------------------------------------------------
// Kernel 1: weighted degree histogram over dst + per-edge slot within row
// ---------------------------------------------------------------------------
__global__ void build_deg_kernel(const int* __restrict__ ei,
                                 const float* __restrict__ w,
                                 float* __restrict__ deg,
                                 int* __restrict__ cnt,
                                 int* __restrict__ slot) {
    int e = blockIdx.x * blockDim.x + threadIdx.x;
    if (e < NE) {
        int d = ei[NE + e];          // dst row of edge_index (2, E)
        atomicAdd(&deg[d], w[e]);
        slot[e] = atomicAdd(&cnt[d], 1);
    }
}

// ---------------------------------------------------------------------------
// Kernel 2 (merged): blocks 0-9 finish_deg; block 10 exclusive scan;
// blocks 11-12 pack W1/W2 into per-lane float2 column pairs.
// W1p[f*32+l] = {W1[f][l], W1[f][l+32]}   (f<32, l<32)
// W2p[j*32+l] = {W2[j][l], W2[j+32][l]}   (j<32, l<32)
// ---------------------------------------------------------------------------
__global__ __launch_bounds__(1024) void mid_kernel(
    const float* __restrict__ deg, float* __restrict__ dis,
    float* __restrict__ selfn,
    const int* __restrict__ cnt, int* __restrict__ rowptr,
    const float* __restrict__ W1, const float* __restrict__ W2,
    float2* __restrict__ W1p, float2* __restrict__ W2p) {
    __shared__ int sm[1024];
    int b = blockIdx.x;
    int tid = threadIdx.x;
    if (b < 10) {                       // dis / selfnorm
        int n = b * 1024 + tid;
        if (n < N_NODES) {
            float d = deg[n] + 1.0f;    // + self-loop weight
            float r = rsqrtf(d);
            dis[n] = r;
            selfn[n] = r * r;
        }
    } else if (b == 10) {               // exclusive scan cnt -> rowptr
        int base = tid * 10;
        int v[10];
        int s = 0;
#pragma unroll
        for (int k = 0; k < 10; ++k) {
            int i = base + k;
            v[k] = (i < N_NODES) ? cnt[i] : 0;
            s += v[k];
        }
        sm[tid] = s;
        __syncthreads();
        for (int off = 1; off < 1024; off <<= 1) {
            int t = (tid >= off) ? sm[tid - off] : 0;
            __syncthreads();
            sm[tid] += t;
            __syncthreads();
        }
        int run = (tid > 0) ? sm[tid - 1] : 0;
#pragma unroll
        for (int k = 0; k < 10; ++k) {
            int i = base + k;
            if (i <= N_NODES) rowptr[i] = run;
            run += v[k];
        }
    } else if (b == 11) {
        int f = tid >> 5, l = tid & 31;
        W1p[tid] = make_float2(W1[f * FH + l], W1[f * FH + 32 + l]);
    } else {
        int j = tid >> 5, l = tid & 31;
        W2p[tid] = make_float2(W2[j * FIN + l], W2[(j + 32) * FIN + l]);
    }
}

// ---------------------------------------------------------------------------
// Kernel 3: scatter edges into dst-sorted CSR, packed {col, norm-bits}
// (slot precomputed in build_deg -> no atomics here)
// ---------------------------------------------------------------------------
__global__ void build_csr_kernel(const int* __restrict__ ei,
                                 const float* __restrict__ w,
                                 const float* __restrict__ dis,
                                 const int* __restrict__ rowptr,
                                 const int* __restrict__ slot,
                                 int2* __restrict__ edges) {
    int e = blockIdx.x * blockDim.x + threadIdx.x;
    if (e < NE) {
        int s = ei[e];
        int d = ei[NE + e];
        int pos = rowptr[d] + slot[e];
        edges[pos] = make_int2(s, __float_as_int(dis[s] * w[e] * dis[d]));
    }
}

// ---------------------------------------------------------------------------
// Kernel 4: transpose x (T,N,F) -> chunk-major xp[tc][n*32+lane] =
// {x[t0,n,lane], x[t0+1,n,lane]}  (node stride 256 B).
// blockIdx = nb*8 + tc: the writing XCD (bid%8) is the one that consumes
// chunk tc in layer1 -> written lines stay in its L2.
// ---------------------------------------------------------------------------
__global__ __launch_bounds__(256) void transpose_kernel(
    const float* __restrict__ x, float2* __restrict__ xp) {
    int b = blockIdx.x;
    int tc = b & (NCHUNK - 1);
    int nb = b >> 3;
    int grp = threadIdx.x >> 5;
    int lane = threadIdx.x & 31;
    int n = nb * 8 + grp;
    const float* x0 = x + (size_t)(tc * TB) * NF + n * FIN + lane;
    xp[(size_t)tc * (N_NODES * 32) + n * 32 + lane] = make_float2(x0[0], x0[NF]);
}

// ---------------------------------------------------------------------------
// Kernel 5 (fused layer 1): block = (t-chunk tc, node-block nb),
// blockIdx = nb*8 + tc pins chunk->XCD (xp slice 2.56 MB, L2-resident from
// the transpose). 512 threads = 16 half-wave groups, one node each, TB=2.
// Gather: ONE float2 load per edge (256 B node stride). Weights LDS-staged;
// only barrier is after staging. Dense phase barrier-free (wave-private LDS).
// ---------------------------------------------------------------------------
#define GPB1 16
__global__ __launch_bounds__(512) void layer1_kernel(
    const float2* __restrict__ xp,
    const int* __restrict__ rowptr,
    const int2* __restrict__ edges,
    const float* __restrict__ selfn,
    const float2* __restrict__ W1p,
    const float* __restrict__ b1,
    const float2* __restrict__ W2p,
    float2* __restrict__ gp) {
    __shared__ float2 sW1p[FIN * 32];       // 8 KB
    __shared__ float2 sW2p[32 * FIN];       // 8 KB
    __shared__ float sB1[FH];               // 256 B
    __shared__ float sAcc[GPB1][TB][FIN];   // 4 KB
    __shared__ float sH[GPB1][TB][FH];      // 8 KB

    int tid = threadIdx.x;
#pragma unroll
    for (int i = 0; i < 2; ++i) sW1p[tid + i * 512] = W1p[tid + i * 512];
#pragma unroll
    for (int i = 0; i < 2; ++i) sW2p[tid + i * 512] = W2p[tid + i * 512];
    if (tid < FH) sB1[tid] = b1[tid];
    __syncthreads();                        // staging visible; groups decouple

    int b = blockIdx.x;
    int tc = b & (NCHUNK - 1);
    int nb = b >> 3;
    int grp = tid >> 5;
    int lane = tid & 31;
    int n = nb * GPB1 + grp;

    const float2* xq = xp + (size_t)tc * (N_NODES * 32) + lane;  // [c*32]

    float sn = selfn[n];
    float2 xs = xq[n * 32];
    float a0 = sn * xs.x;
    float a1 = sn * xs.y;

    int e = rowptr[n], e1 = rowptr[n + 1];
    for (; e + 4 <= e1; e += 4) {
        int2 p0 = edges[e], p1 = edges[e + 1], p2 = edges[e + 2], p3 = edges[e + 3];
        float2 q0 = xq[p0.x * 32], q1 = xq[p1.x * 32];
        float2 q2 = xq[p2.x * 32], q3 = xq[p3.x * 32];
        float v0 = __int_as_float(p0.y), v1 = __int_as_float(p1.y);
        float v2 = __int_as_float(p2.y), v3 = __int_as_float(p3.y);
        a0 = fmaf(v0, q0.x, a0); a1 = fmaf(v0, q0.y, a1);
        a0 = fmaf(v1, q1.x, a0); a1 = fmaf(v1, q1.y, a1);
        a0 = fmaf(v2, q2.x, a0); a1 = fmaf(v2, q2.y, a1);
        a0 = fmaf(v3, q3.x, a0); a1 = fmaf(v3, q3.y, a1);
    }
    for (; e < e1; ++e) {
        int2 p = edges[e];
        float v = __int_as_float(p.y);
        float2 q = xq[p.x * 32];
        a0 = fmaf(v, q.x, a0);
        a1 = fmaf(v, q.y, a1);
    }

    // ---- dense: h = relu(acc @ W1 + b1); g = h @ W2  (no barriers) ----
    sAcc[grp][0][lane] = a0;
    sAcc[grp][1][lane] = a1;
    float h0 = sB1[lane];
    float h1 = sB1[lane + 32];
    float h2 = h0, h3 = h1;
#pragma unroll
    for (int f = 0; f < FIN; ++f) {
        float2 w = sW1p[f * 32 + lane];
        float af0 = sAcc[grp][0][f];   // same-wave LDS broadcast
        float af1 = sAcc[grp][1][f];
        h0 = fmaf(af0, w.x, h0); h1 = fmaf(af0, w.y, h1);
        h2 = fmaf(af1, w.x, h2); h3 = fmaf(af1, w.y, h3);
    }
    sH[grp][0][lane] = fmaxf(h0, 0.0f);
    sH[grp][0][lane + 32] = fmaxf(h1, 0.0f);
    sH[grp][1][lane] = fmaxf(h2, 0.0f);
    sH[grp][1][lane + 32] = fmaxf(h3, 0.0f);
    float g0 = 0.0f, g1 = 0.0f;
#pragma unroll
    for (int j = 0; j < 32; ++j) {
        float2 w = sW2p[j * 32 + lane];
        g0 = fmaf(sH[grp][0][j], w.x, g0);
        g0 = fmaf(sH[grp][0][j + 32], w.y, g0);
        g1 = fmaf(sH[grp][1][j], w.x, g1);
        g1 = fmaf(sH[grp][1][j + 32], w.y, g1);
    }
    // chunk-major: gp[tc][n][lane] -> node stride 256 B
    gp[(size_t)tc * (N_NODES * 32) + n * 32 + lane] = make_float2(g0, g1);
}

// ---------------------------------------------------------------------------
// Kernel 6 (layer 2 aggregation): unchanged from round 7 (proven pattern).
// ---------------------------------------------------------------------------
__global__ __launch_bounds__(256) void layer2_kernel(
    const float2* __restrict__ gp,
    const int* __restrict__ rowptr,
    const int2* __restrict__ edges,
    const float* __restrict__ selfn,
    const float* __restrict__ b2,
    float* __restrict__ out, int out_size) {
    int b = blockIdx.x;
    int tc = b & (NCHUNK - 1);
    int nb = b >> 3;
    int tid = threadIdx.x;
    int grp = tid >> 5;
    int lane = tid & 31;
    int n = nb * 8 + grp;

    const float2* gq = gp + (size_t)tc * (N_NODES * 32) + lane;  // [c*32]

    float sn = selfn[n];
    float bb = b2[lane];
    float2 gs = gq[n * 32];
    float a0 = fmaf(sn, gs.x, bb);
    float a1 = fmaf(sn, gs.y, bb);

    int e = rowptr[n], e1 = rowptr[n + 1];
    for (; e + 4 <= e1; e += 4) {
        int2 p0 = edges[e], p1 = edges[e + 1], p2 = edges[e + 2], p3 = edges[e + 3];
        float2 q0 = gq[p0.x * 32], q1 = gq[p1.x * 32];
        float2 q2 = gq[p2.x * 32], q3 = gq[p3.x * 32];
        float v0 = __int_as_float(p0.y), v1 = __int_as_float(p1.y);
        float v2 = __int_as_float(p2.y), v3 = __int_as_float(p3.y);
        a0 = fmaf(v0, q0.x, a0); a1 = fmaf(v0, q0.y, a1);
        a0 = fmaf(v1, q1.x, a0); a1 = fmaf(v1, q1.y, a1);
        a0 = fmaf(v2, q2.x, a0); a1 = fmaf(v2, q2.y, a1);
        a0 = fmaf(v3, q3.x, a0); a1 = fmaf(v3, q3.y, a1);
    }
    for (; e < e1; ++e) {
        int2 p = edges[e];
        float v = __int_as_float(p.y);
        float2 q = gq[p.x * 32];
        a0 = fmaf(v, q.x, a0);
        a1 = fmaf(v, q.y, a1);
    }

    int t0 = tc * TB;
    out[(size_t)t0 * NF + n * FIN + lane] = a0;
    out[(size_t)t0 * NF + NF + n * FIN + lane] = a1;

    // second tuple element (scalar 0) and any tail
    if (b == 0 && tid == 0) {
        for (int i = T_DIM * NF; i < out_size; ++i) out[i] = 0.0f;
    }
}

// ---------------------------------------------------------------------------
extern "C" void kernel_launch(void* const* d_in, const int* in_sizes, int n_in,
                              void* d_out, int out_size, void* d_ws, size_t ws_size,
                              hipStream_t stream) {
    const float* x  = (const float*)d_in[0];
    const int*   ei = (const int*)d_in[1];     // (2, E) int32: [src | dst]
    const float* w  = (const float*)d_in[2];
    // d_in[3] missing_mask: unused by reference math
    const float* W1 = (const float*)d_in[4];
    const float* b1 = (const float*)d_in[5];
    const float* W2 = (const float*)d_in[6];
    const float* b2 = (const float*)d_in[7];
    float* out = (float*)d_out;

    char* p = (char*)d_ws;
    float2* xp    = (float2*)p; p += sizeof(float2) * (size_t)N_NODES * NCHUNK * 32;
    float2* gp    = (float2*)p; p += sizeof(float2) * (size_t)N_NODES * NCHUNK * 32;
    // deg, cnt contiguous -> single memset
    float* deg    = (float*)p; p += sizeof(float) * N_NODES;
    int*   cnt    = (int*)p;   p += sizeof(int) * N_NODES;
    float* dis    = (float*)p; p += sizeof(float) * N_NODES;
    float* selfn  = (float*)p; p += sizeof(float) * N_NODES;
    int*   rowptr = (int*)p;   p += sizeof(int) * (N_NODES + 1);
    int*   slot   = (int*)p;   p += sizeof(int) * NE;
    int2*  edges  = (int2*)p;  p += sizeof(int2) * NE;
    float2* W1p   = (float2*)p; p += sizeof(float2) * FIN * 32;
    float2* W2p   = (float2*)p; p += sizeof(float2) * 32 * FIN;

    hipMemsetAsync(deg, 0, sizeof(float) * N_NODES * 2, stream);

    build_deg_kernel<<<(NE + 255) / 256, 256, 0, stream>>>(ei, w, deg, cnt, slot);
    mid_kernel<<<13, 1024, 0, stream>>>(deg, dis, selfn, cnt, rowptr,
                                        W1, W2, W1p, W2p);
    build_csr_kernel<<<(NE + 255) / 256, 256, 0, stream>>>(ei, w, dis, rowptr,
                                                           slot, edges);
    transpose_kernel<<<(N_NODES / 8) * NCHUNK, 256, 0, stream>>>(x, xp);
    layer1_kernel<<<(N_NODES / GPB1) * NCHUNK, 512, 0, stream>>>(
        xp, rowptr, edges, selfn, W1p, b1, W2p, gp);
    layer2_kernel<<<(N_NODES / 8) * NCHUNK, 256, 0, stream>>>(
        gp, rowptr, edges, selfn, b2, out, out_size);
}

// Round 9
// 225.810 us; speedup vs baseline: 1.0496x; 1.0496x over previous
//
#include <hip/hip_runtime.h>
#include <hip/hip_bf16.h>

// Problem constants (from reference)
#define T_DIM   16
#define N_NODES 10000
#define FIN     32
#define FH      64
#define NE      160000
#define TB      2              // timesteps per chunk
#define NCHUNK  (T_DIM / TB)   // 8 chunks -> one per XCD via bid%8
#define NF      (N_NODES * FIN)
#define REC     64             // floats per node record: 2 t-halves x 32 f
#define WPB     8              // waves (nodes) per 512-thread block

// ---------------------------------------------------------------------------
// Kernel 1 (merged): blocks 0..19999 transpose x -> xpN (uniform-wave layout,
// XCD-pinned: writer bid%8 == consumer tc); blocks 20000..20624 degree
// histogram + per-edge slot.
// xpN[tc][n*64 + th*32 + f] = x[tc*2+th][n][f]
// ---------------------------------------------------------------------------
__global__ __launch_bounds__(256) void prep_kernel(
    const float* __restrict__ x, float* __restrict__ xpN,
    const int* __restrict__ ei, const float* __restrict__ w,
    float* __restrict__ deg, int* __restrict__ cnt, int* __restrict__ slot) {
    int b = blockIdx.x;
    int tid = threadIdx.x;
    if (b < 20000) {
        int tc = b & 7;
        int nb = b >> 3;                 // 0..2499
        int f = tid & 31, th = (tid >> 5) & 1, ns = tid >> 6;
        int n = nb * 4 + ns;
        xpN[(size_t)tc * (N_NODES * REC) + n * REC + th * 32 + f] =
            x[(size_t)(tc * TB + th) * NF + n * FIN + f];
    } else {
        int e = (b - 20000) * 256 + tid;
        if (e < NE) {
            int d = ei[NE + e];          // dst row of edge_index (2, E)
            atomicAdd(&deg[d], w[e]);
            slot[e] = atomicAdd(&cnt[d], 1);
        }
    }
}

// ---------------------------------------------------------------------------
// Kernel 2: blocks 0-9 dis/selfnorm; block 10 exclusive scan cnt -> rowptr
// ---------------------------------------------------------------------------
__global__ __launch_bounds__(1024) void mid_kernel(
    const float* __restrict__ deg, float* __restrict__ dis,
    float* __restrict__ selfn,
    const int* __restrict__ cnt, int* __restrict__ rowptr) {
    __shared__ int sm[1024];
    int b = blockIdx.x;
    int tid = threadIdx.x;
    if (b < 10) {                        // dis / selfnorm
        int n = b * 1024 + tid;
        if (n < N_NODES) {
            float d = deg[n] + 1.0f;     // + self-loop weight
            float r = rsqrtf(d);
            dis[n] = r;
            selfn[n] = r * r;
        }
    } else {                             // exclusive scan
        int base = tid * 10;
        int v[10];
        int s = 0;
#pragma unroll
        for (int k = 0; k < 10; ++k) {
            int i = base + k;
            v[k] = (i < N_NODES) ? cnt[i] : 0;
            s += v[k];
        }
        sm[tid] = s;
        __syncthreads();
        for (int off = 1; off < 1024; off <<= 1) {
            int t = (tid >= off) ? sm[tid - off] : 0;
            __syncthreads();
            sm[tid] += t;
            __syncthreads();
        }
        int run = (tid > 0) ? sm[tid - 1] : 0;
#pragma unroll
        for (int k = 0; k < 10; ++k) {
            int i = base + k;
            if (i <= N_NODES) rowptr[i] = run;
            run += v[k];
        }
    }
}

// ---------------------------------------------------------------------------
// Kernel 3: scatter edges into dst-sorted CSR, packed {col, norm-bits}
// ---------------------------------------------------------------------------
__global__ void build_csr_kernel(const int* __restrict__ ei,
                                 const float* __restrict__ w,
                                 const float* __restrict__ dis,
                                 const int* __restrict__ rowptr,
                                 const int* __restrict__ slot,
                                 int2* __restrict__ edges) {
    int e = blockIdx.x * blockDim.x + threadIdx.x;
    if (e < NE) {
        int s = ei[e];
        int d = ei[NE + e];
        int pos = rowptr[d] + slot[e];
        edges[pos] = make_int2(s, __float_as_int(dis[s] * w[e] * dis[d]));
    }
}

// Uniform-wave CSR gather: acc += val * src[col*REC + l]; everything except
// the gathered value is wave-uniform (scalar pipe / 1-address loads).
#define GATHER(Q)                                                           \
    for (; e + 4 <= e1; e += 4) {                                           \
        int2 p0 = edges[e], p1 = edges[e + 1];                              \
        int2 p2 = edges[e + 2], p3 = edges[e + 3];                          \
        float q0 = Q[p0.x * REC + l], q1 = Q[p1.x * REC + l];               \
        float q2 = Q[p2.x * REC + l], q3 = Q[p3.x * REC + l];               \
        acc = fmaf(__int_as_float(p0.y), q0, acc);                          \
        acc = fmaf(__int_as_float(p1.y), q1, acc);                          \
        acc = fmaf(__int_as_float(p2.y), q2, acc);                          \
        acc = fmaf(__int_as_float(p3.y), q3, acc);                          \
    }                                                                       \
    for (; e < e1; ++e) {                                                   \
        int2 p = edges[e];                                                  \
        acc = fmaf(__int_as_float(p.y), Q[p.x * REC + l], acc);             \
    }

// ---------------------------------------------------------------------------
// Kernel 4 (fused layer 1): ONE WAVE PER NODE (lane = f + 32*th), TB=2.
// blockIdx = nb*8 + tc pins chunk->XCD (xpN slice 2.56 MB, L2-resident).
// Gather: 1 dword load + 1 fmac per lane per edge, uniform control flow.
// Dense: h[j=l] for both t (shared weight reg), then g[k=l&31, t=l>>5].
// Weights LDS-staged; only barrier is after staging; sAcc/sH wave-private.
// ---------------------------------------------------------------------------
__global__ __launch_bounds__(512) void layer1_kernel(
    const float* __restrict__ xpN,
    const int* __restrict__ rowptr,
    const int2* __restrict__ edges,
    const float* __restrict__ selfn,
    const float* __restrict__ W1,
    const float* __restrict__ b1,
    const float* __restrict__ W2,
    float* __restrict__ gpN) {
    __shared__ float sW1[FIN * FH];            // 8 KB  [f*64 + j]
    __shared__ float sW2[FH * FIN];            // 8 KB  [j*32 + k]
    __shared__ float sB1[FH];                  // 256 B
    __shared__ float2 sAcc2[WPB][FIN];         // 2 KB  [w][f] = {t0, t1}
    __shared__ float2 sH2[WPB][TB][FH / 2];    // 4 KB  [w][t][j/2]

    int tid = threadIdx.x;
    for (int i = tid; i < FIN * FH; i += 512) sW1[i] = W1[i];
    for (int i = tid; i < FH * FIN; i += 512) sW2[i] = W2[i];
    if (tid < FH) sB1[tid] = b1[tid];
    __syncthreads();                           // staging visible; waves decouple

    int bck = blockIdx.x;
    int tc = bck & 7;
    int nb = bck >> 3;
    int wv = __builtin_amdgcn_readfirstlane(tid >> 6);
    int l = tid & 63;
    int n = nb * WPB + wv;

    const float* xq = xpN + (size_t)tc * (N_NODES * REC);

    float acc = selfn[n] * xq[n * REC + l];
    int e = rowptr[n], e1 = rowptr[n + 1];
    GATHER(xq)

    // ---- dense (wave-private, no barriers) ----
    int f = l & 31, th = l >> 5;
    ((float*)&sAcc2[wv][f])[th] = acc;

    float h0 = sB1[l];                         // j = l, t0
    float h1 = h0;                             // j = l, t1
#pragma unroll
    for (int ff = 0; ff < FIN; ++ff) {
        float2 af = sAcc2[wv][ff];             // broadcast {t0, t1}
        float wj = sW1[ff * FH + l];
        h0 = fmaf(af.x, wj, h0);
        h1 = fmaf(af.y, wj, h1);
    }
    float* ph = (float*)sH2[wv];               // [0..63]=t0, [64..127]=t1
    ph[l] = fmaxf(h0, 0.0f);
    ph[64 + l] = fmaxf(h1, 0.0f);

    float g = 0.0f;                            // k = f, t = th
#pragma unroll
    for (int j2 = 0; j2 < FH / 2; ++j2) {
        float2 hh = sH2[wv][th][j2];           // 2-address broadcast
        g = fmaf(hh.x, sW2[(2 * j2) * FIN + f], g);
        g = fmaf(hh.y, sW2[(2 * j2 + 1) * FIN + f], g);
    }
    gpN[(size_t)tc * (N_NODES * REC) + n * REC + l] = g;
}

// ---------------------------------------------------------------------------
// Kernel 5 (layer 2 aggregation): same uniform-wave structure, no LDS.
// gpN slice written by the same XCD in layer1 -> L2-local. out (T,N,F) + b2.
// ---------------------------------------------------------------------------
__global__ __launch_bounds__(512) void layer2_kernel(
    const float* __restrict__ gpN,
    const int* __restrict__ rowptr,
    const int2* __restrict__ edges,
    const float* __restrict__ selfn,
    const float* __restrict__ b2,
    float* __restrict__ out, int out_size) {
    int bck = blockIdx.x;
    int tc = bck & 7;
    int nb = bck >> 3;
    int tid = threadIdx.x;
    int wv = __builtin_amdgcn_readfirstlane(tid >> 6);
    int l = tid & 63;
    int n = nb * WPB + wv;
    int f = l & 31, th = l >> 5;

    const float* gq = gpN + (size_t)tc * (N_NODES * REC);

    float acc = b2[f] + selfn[n] * gq[n * REC + l];
    int e = rowptr[n], e1 = rowptr[n + 1];
    GATHER(gq)

    out[(size_t)(tc * TB + th) * NF + n * FIN + f] = acc;

    // second tuple element (scalar 0) and any tail
    if (bck == 0 && tid == 0) {
        for (int i = T_DIM * NF; i < out_size; ++i) out[i] = 0.0f;
    }
}

// ---------------------------------------------------------------------------
extern "C" void kernel_launch(void* const* d_in, const int* in_sizes, int n_in,
                              void* d_out, int out_size, void* d_ws, size_t ws_size,
                              hipStream_t stream) {
    const float* x  = (const float*)d_in[0];
    const int*   ei = (const int*)d_in[1];     // (2, E) int32: [src | dst]
    const float* w  = (const float*)d_in[2];
    // d_in[3] missing_mask: unused by reference math
    const float* W1 = (const float*)d_in[4];
    const float* b1 = (const float*)d_in[5];
    const float* W2 = (const float*)d_in[6];
    const float* b2 = (const float*)d_in[7];
    float* out = (float*)d_out;

    char* p = (char*)d_ws;
    float* xpN    = (float*)p; p += sizeof(float) * (size_t)N_NODES * REC * NCHUNK;
    float* gpN    = (float*)p; p += sizeof(float) * (size_t)N_NODES * REC * NCHUNK;
    // deg, cnt contiguous -> single memset
    float* deg    = (float*)p; p += sizeof(float) * N_NODES;
    int*   cnt    = (int*)p;   p += sizeof(int) * N_NODES;
    float* dis    = (float*)p; p += sizeof(float) * N_NODES;
    float* selfn  = (float*)p; p += sizeof(float) * N_NODES;
    int*   rowptr = (int*)p;   p += sizeof(int) * (N_NODES + 1);
    int*   slot   = (int*)p;   p += sizeof(int) * NE;
    int2*  edges  = (int2*)p;  p += sizeof(int2) * NE;

    hipMemsetAsync(deg, 0, sizeof(float) * N_NODES * 2, stream);

    prep_kernel<<<20000 + (NE + 255) / 256, 256, 0, stream>>>(
        x, xpN, ei, w, deg, cnt, slot);
    mid_kernel<<<11, 1024, 0, stream>>>(deg, dis, selfn, cnt, rowptr);
    build_csr_kernel<<<(NE + 255) / 256, 256, 0, stream>>>(ei, w, dis, rowptr,
                                                           slot, edges);
    layer1_kernel<<<(N_NODES / WPB) * NCHUNK, 512, 0, stream>>>(
        xpN, rowptr, edges, selfn, W1, b1, W2, gpN);
    layer2_kernel<<<(N_NODES / WPB) * NCHUNK, 512, 0, stream>>>(
        gpN, rowptr, edges, selfn, b2, out, out_size);
}